// Round 7
// baseline (592.502 us; speedup 1.0000x reference)
//
#include <hip/hip_runtime.h>
#include <hip/hip_bf16.h>

#define LRELU_SLOPE 0.2f

__device__ __forceinline__ float lrelu(float x) { return x > 0.f ? x : LRELU_SLOPE * x; }

// ---------------- utility kernels ----------------
__global__ void k_zero(int* __restrict__ a, int n) {
    int i = blockIdx.x * blockDim.x + threadIdx.x;
    if (i < n) a[i] = 0;
}

__global__ void k_hist(const int* __restrict__ dst, int* __restrict__ deg, int E) {
    int i = blockIdx.x * blockDim.x + threadIdx.x;
    if (i < E) atomicAdd(&deg[dst[i]], 1);
}

// block-level exclusive scan over 1024 elements; writes per-block totals
__global__ __launch_bounds__(1024) void k_scan1(const int* __restrict__ deg, int* __restrict__ off,
                                                int* __restrict__ bsums, int N) {
    int t = threadIdx.x, b = blockIdx.x;
    int idx = b * 1024 + t;
    int v = (idx < N) ? deg[idx] : 0;
    int lane = t & 63, wid = t >> 6;
    int incl = v;
    #pragma unroll
    for (int d = 1; d < 64; d <<= 1) {
        int u = __shfl_up(incl, d);
        if (lane >= d) incl += u;
    }
    __shared__ int ws[16];
    if (lane == 63) ws[wid] = incl;
    __syncthreads();
    if (wid == 0) {
        int wv = (lane < 16) ? ws[lane] : 0;
        #pragma unroll
        for (int d = 1; d < 16; d <<= 1) {
            int u = __shfl_up(wv, d);
            if (lane >= d) wv += u;
        }
        if (lane < 16) ws[lane] = wv;  // inclusive wave sums
    }
    __syncthreads();
    int woff = (wid > 0) ? ws[wid - 1] : 0;
    if (idx < N) off[idx] = woff + incl - v;  // exclusive within block
    if (t == 0) bsums[b] = ws[15];            // block total
}

// single-block exclusive scan of up to 1024 block sums
__global__ __launch_bounds__(1024) void k_scan2(int* __restrict__ bs, int nb) {
    __shared__ int s[1024];
    int t = threadIdx.x;
    s[t] = (t < nb) ? bs[t] : 0;
    __syncthreads();
    for (int d = 1; d < 1024; d <<= 1) {
        int v = (t >= d) ? s[t - d] : 0;
        __syncthreads();
        s[t] += v;
        __syncthreads();
    }
    if (t < nb) bs[t] = t ? s[t - 1] : 0;
}

__global__ __launch_bounds__(1024) void k_scan3(int* __restrict__ off, const int* __restrict__ bs, int N) {
    int i = blockIdx.x * 1024 + threadIdx.x;
    if (i < N) off[i] += bs[blockIdx.x];
}

__global__ void k_scatter(const int* __restrict__ src, const int* __restrict__ dst,
                          const int* __restrict__ off, int* __restrict__ cur,
                          int* __restrict__ csr, int E) {
    int i = blockIdx.x * blockDim.x + threadIdx.x;
    if (i < E) {
        int d = dst[i];
        int pos = off[d] + atomicAdd(&cur[d], 1);
        csr[pos] = src[i];
    }
}

// ---------------- GEMM: XW = X[N,K] @ W[K,64], fused attention logits ----------------
// ROW-PER-LANE layout (r7): lane owns one row, acc[64] per lane; W[k][*] is
// wave-uniform -> compiler emits s_load into SGPRs; v_fmac_f32 v,s,v uses the
// broadcast operand for free. Per k: one 4B per-lane X load (L1 line reused
// across 16 consecutive k) + 64 FMAs -> 1 VMEM : 64 FMA. No LDS, no staging,
// no barrier. Replaces the col-per-lane scheme whose 1 ds_read_b128 : 4 FMA
// ratio made the LDS issue pipe the ceiling (r6: VALUBusy 54%, 127 us).
// REGISTER-PRESSURE HISTORY (do not regress):
//   r3: __launch_bounds__(256,4) VGPR=64 clamp -> spill -> 2.4 GB scratch.
//   r4: straight-line K=64 body -> scheduler clustered all loads -> VGPR=256 spill.
//   r5: sched_barrier(0) did NOT stop the clustering (useless on this compiler).
//   r6: dynamic (unroll-disabled) loop = the only reliable scope bound.
template <int K>
__global__ __launch_bounds__(256) void k_gemm(const float* __restrict__ X, const float* __restrict__ W,
                                              const float* __restrict__ a_s, const float* __restrict__ a_d,
                                              float* __restrict__ XW, float* __restrict__ Ssrc,
                                              float* __restrict__ Sdst, int N) {
    int t = threadIdx.x, lane = t & 63, wid = t >> 6;
    int row = blockIdx.x * 256 + wid * 64 + lane;
    int rowc = row < N ? row : N - 1;  // clamp (loads only; no write for OOB)
    const float* xp = X + (size_t)rowc * K;

    float acc[64];
    #pragma unroll
    for (int c = 0; c < 64; c++) acc[c] = 0.f;

    // dynamic loop: body = 1 global_load_dword + 4 s_load_dwordx16 + 64 v_fmac.
    // ~80 live VGPR worst case; SMEM/VMEM latency hidden by ~6 waves/SIMD TLP.
    #pragma clang loop unroll(disable)
    for (int k = 0; k < K; k++) {
        float xv = xp[k];
        const float* wk = W + (size_t)k * 64;  // wave-uniform -> s_load
        #pragma unroll
        for (int c = 0; c < 64; c++) acc[c] += xv * wk[c];
    }

    if (row < N) {
        // attention logits: a_s/a_d wave-uniform -> SGPR broadcast, no shuffles
        float vs = 0.f, vd = 0.f;
        #pragma unroll
        for (int c = 0; c < 64; c++) {
            vs += acc[c] * a_s[c];
            vd += acc[c] * a_d[c];
        }
        Ssrc[row] = vs;
        Sdst[row] = vd;
        // row store: 16 dwordx4; successive stores fill each 64B line fully,
        // L2 write-combines -> HBM write stays ~26 MB
        float4* op = (float4*)(XW + (size_t)row * 64);
        #pragma unroll
        for (int c4 = 0; c4 < 16; c4++)
            op[c4] = make_float4(acc[c4 * 4], acc[c4 * 4 + 1], acc[c4 * 4 + 2], acc[c4 * 4 + 3]);
    }
}

// ---------------- attention + aggregate: one wave per dst node ----------------
__global__ __launch_bounds__(256) void k_attn(const float* __restrict__ XW, const float* __restrict__ Ssrc,
                                              const float* __restrict__ Sdst, const int* __restrict__ csr,
                                              const int* __restrict__ off, const int* __restrict__ deg,
                                              const float* __restrict__ bias, float* __restrict__ H,
                                              int N, int do_relu) {
    int t = threadIdx.x, lane = t & 63, wid = t >> 6;
    int n = blockIdx.x * 4 + wid;
    if (n >= N) return;
    float sd = Sdst[n];
    int st = off[n], d = deg[n];

    // phase 1: max over edges (lanes parallel over edges); cache first 64 src/e in regs
    float eself = lrelu(Ssrc[n] + sd);
    float m = eself;
    int myS = 0;
    float myE = -1e30f;
    if (lane < d) {
        myS = csr[st + lane];
        myE = lrelu(Ssrc[myS] + sd);
        m = fmaxf(m, myE);
    }
    for (int i = 64 + lane; i < d; i += 64) {
        int s = csr[st + i];
        m = fmaxf(m, lrelu(Ssrc[s] + sd));
    }
    #pragma unroll
    for (int dd = 32; dd > 0; dd >>= 1) m = fmaxf(m, __shfl_xor(m, dd));

    // phase 2: serial over edges, lanes = feature dims
    float w0 = __expf(eself - m);
    float denom = w0;
    float acc = w0 * XW[(size_t)n * 64 + lane];
    int dcap = d < 64 ? d : 64;
    for (int i = 0; i < dcap; i++) {
        int s = __shfl(myS, i);
        float e = __shfl(myE, i);
        float w = __expf(e - m);
        denom += w;
        acc += w * XW[(size_t)s * 64 + lane];
    }
    for (int i = 64; i < d; i++) {
        int s = csr[st + i];
        float e = lrelu(Ssrc[s] + sd);
        float w = __expf(e - m);
        denom += w;
        acc += w * XW[(size_t)s * 64 + lane];
    }
    float o = acc / denom + bias[lane];
    if (do_relu) o = fmaxf(o, 0.f);
    H[(size_t)n * 64 + lane] = o;
}

// ---------------- head: out[i] = [h[u]; h[m]] . fcW + fcb ----------------
__global__ __launch_bounds__(256) void k_head(const float* __restrict__ H, const int* __restrict__ ui,
                                              const int* __restrict__ mi, const float* __restrict__ fcW,
                                              const float* __restrict__ fcb, float* __restrict__ out, int B) {
    int t = threadIdx.x, lane = t & 63, wid = t >> 6;
    int i = blockIdx.x * 4 + wid;
    if (i >= B) return;
    int u = ui[i], m = mi[i];
    float v = H[(size_t)u * 64 + lane] * fcW[lane] + H[(size_t)m * 64 + lane] * fcW[64 + lane];
    #pragma unroll
    for (int dd = 32; dd > 0; dd >>= 1) v += __shfl_xor(v, dd);
    if (lane == 0) out[i] = v + fcb[0];
}

extern "C" void kernel_launch(void* const* d_in, const int* in_sizes, int n_in,
                              void* d_out, int out_size, void* d_ws, size_t ws_size,
                              hipStream_t stream) {
    const float* x   = (const float*)d_in[0];
    const int*   ei  = (const int*)d_in[1];
    const int*   ui  = (const int*)d_in[2];
    const int*   mi  = (const int*)d_in[3];
    const float* W1  = (const float*)d_in[4];
    const float* as1 = (const float*)d_in[5];
    const float* ad1 = (const float*)d_in[6];
    const float* b1  = (const float*)d_in[7];
    const float* W2  = (const float*)d_in[8];
    const float* as2 = (const float*)d_in[9];
    const float* ad2 = (const float*)d_in[10];
    const float* b2  = (const float*)d_in[11];
    const float* fcW = (const float*)d_in[12];
    const float* fcb = (const float*)d_in[13];
    float* out = (float*)d_out;

    const int Hdim = in_sizes[5];            // 64
    const int FIN  = in_sizes[4] / Hdim;     // 256
    const int N    = in_sizes[0] / FIN;      // 100000
    const int E    = in_sizes[1] / 2;        // 1000000
    const int B    = in_sizes[2];            // 16384

    // workspace carve
    char* w = (char*)d_ws;
    auto alloc = [&](size_t bytes) -> void* {
        void* p = (void*)w;
        w += (bytes + 255) & ~(size_t)255;
        return p;
    };
    float* xw   = (float*)alloc((size_t)N * 64 * 4);
    float* hbuf = (float*)alloc((size_t)N * 64 * 4);
    float* ssrc = (float*)alloc((size_t)N * 4);
    float* sdst = (float*)alloc((size_t)N * 4);
    int* degcur = (int*)alloc((size_t)2 * N * 4);  // deg | cur contiguous
    int* deg = degcur;
    int* cur = degcur + N;
    int* offv  = (int*)alloc((size_t)N * 4);
    int* bsums = (int*)alloc((size_t)1024 * 4);
    int* csr   = (int*)alloc((size_t)E * 4);

    const int* esrc = ei;
    const int* edst = ei + E;

    // --- build CSR by dst (shared by both layers) ---
    k_zero<<<(2 * N + 1023) / 1024, 1024, 0, stream>>>(degcur, 2 * N);
    k_hist<<<(E + 255) / 256, 256, 0, stream>>>(edst, deg, E);
    int nb = (N + 1023) / 1024;
    k_scan1<<<nb, 1024, 0, stream>>>(deg, offv, bsums, N);
    k_scan2<<<1, 1024, 0, stream>>>(bsums, nb);
    k_scan3<<<nb, 1024, 0, stream>>>(offv, bsums, N);
    k_scatter<<<(E + 255) / 256, 256, 0, stream>>>(esrc, edst, offv, cur, csr, E);

    const int gemmBlocks = (N + 255) / 256;

    // --- layer 1 ---
    k_gemm<256><<<gemmBlocks, 256, 0, stream>>>(x, W1, as1, ad1, xw, ssrc, sdst, N);
    k_attn<<<(N + 3) / 4, 256, 0, stream>>>(xw, ssrc, sdst, csr, offv, deg, b1, hbuf, N, 1);

    // --- layer 2 (xw buffer reused) ---
    k_gemm<64><<<gemmBlocks, 256, 0, stream>>>(hbuf, W2, as2, ad2, xw, ssrc, sdst, N);
    k_attn<<<(N + 3) / 4, 256, 0, stream>>>(xw, ssrc, sdst, csr, offv, deg, b2, hbuf, N, 0);

    // --- head ---
    k_head<<<(B + 3) / 4, 256, 0, stream>>>(hbuf, ui, mi, fcW, fcb, out, B);
}

// Round 8
// 585.562 us; speedup vs baseline: 1.0119x; 1.0119x over previous
//
#include <hip/hip_runtime.h>
#include <hip/hip_bf16.h>

#define LRELU_SLOPE 0.2f

__device__ __forceinline__ float lrelu(float x) { return x > 0.f ? x : LRELU_SLOPE * x; }

// ---------------- utility kernels ----------------
__global__ void k_zero(int* __restrict__ a, int n) {
    int i = blockIdx.x * blockDim.x + threadIdx.x;
    if (i < n) a[i] = 0;
}

__global__ void k_hist(const int* __restrict__ dst, int* __restrict__ deg, int E) {
    int i = blockIdx.x * blockDim.x + threadIdx.x;
    if (i < E) atomicAdd(&deg[dst[i]], 1);
}

// block-level exclusive scan over 1024 elements; writes per-block totals
__global__ __launch_bounds__(1024) void k_scan1(const int* __restrict__ deg, int* __restrict__ off,
                                                int* __restrict__ bsums, int N) {
    int t = threadIdx.x, b = blockIdx.x;
    int idx = b * 1024 + t;
    int v = (idx < N) ? deg[idx] : 0;
    int lane = t & 63, wid = t >> 6;
    int incl = v;
    #pragma unroll
    for (int d = 1; d < 64; d <<= 1) {
        int u = __shfl_up(incl, d);
        if (lane >= d) incl += u;
    }
    __shared__ int ws[16];
    if (lane == 63) ws[wid] = incl;
    __syncthreads();
    if (wid == 0) {
        int wv = (lane < 16) ? ws[lane] : 0;
        #pragma unroll
        for (int d = 1; d < 16; d <<= 1) {
            int u = __shfl_up(wv, d);
            if (lane >= d) wv += u;
        }
        if (lane < 16) ws[lane] = wv;  // inclusive wave sums
    }
    __syncthreads();
    int woff = (wid > 0) ? ws[wid - 1] : 0;
    if (idx < N) off[idx] = woff + incl - v;  // exclusive within block
    if (t == 0) bsums[b] = ws[15];            // block total
}

// single-block exclusive scan of up to 1024 block sums
__global__ __launch_bounds__(1024) void k_scan2(int* __restrict__ bs, int nb) {
    __shared__ int s[1024];
    int t = threadIdx.x;
    s[t] = (t < nb) ? bs[t] : 0;
    __syncthreads();
    for (int d = 1; d < 1024; d <<= 1) {
        int v = (t >= d) ? s[t - d] : 0;
        __syncthreads();
        s[t] += v;
        __syncthreads();
    }
    if (t < nb) bs[t] = t ? s[t - 1] : 0;
}

__global__ __launch_bounds__(1024) void k_scan3(int* __restrict__ off, const int* __restrict__ bs, int N) {
    int i = blockIdx.x * 1024 + threadIdx.x;
    if (i < N) off[i] += bs[blockIdx.x];
}

__global__ void k_scatter(const int* __restrict__ src, const int* __restrict__ dst,
                          const int* __restrict__ off, int* __restrict__ cur,
                          int* __restrict__ csr, int E) {
    int i = blockIdx.x * blockDim.x + threadIdx.x;
    if (i < E) {
        int d = dst[i];
        int pos = off[d] + atomicAdd(&cur[d], 1);
        csr[pos] = src[i];
    }
}

// ---------------- GEMM: XW = X[N,K] @ W[K,64], fused attention logits ----------------
// ROW-PER-LANE (r7) + X SOFTWARE PIPELINE (r8). Lane owns one row; W[k][*] is
// wave-uniform -> s_load into 64 SGPRs, FMA uses the SGPR broadcast operand
// for free (1 VMEM : 64 FMA). TLP is structurally capped at N/64 = 1563 waves
// = 1.5 waves/SIMD (r7 post-mortem: occupancy 17%, VALUBusy 14.5% — the x
// load latency was fully exposed). So hide it in-wave: dynamic loop over
// 4-k steps; each body consumes the float4 of x prefetched by the PREVIOUS
// body (~900 cyc of cover) and issues the next. W s_loads stay per single k:
// 64 SGPR live; a 4-k body cannot cluster past the ~102-SGPR file, so the
// r4-style load-clustering blowup cannot recur in SGPR space.
// REGISTER-PRESSURE HISTORY (do not regress):
//   r3: __launch_bounds__(256,4) VGPR=64 clamp -> spill -> 2.4 GB scratch.
//   r4: straight-line body -> scheduler clustered all loads -> VGPR=256 spill.
//   r5: sched_barrier(0) did NOT stop the clustering (useless on this compiler).
//   r6: dynamic (unroll-disabled) loop = the only reliable scope bound.
template <int K>
__global__ __launch_bounds__(256) void k_gemm(const float* __restrict__ X, const float* __restrict__ W,
                                              const float* __restrict__ a_s, const float* __restrict__ a_d,
                                              float* __restrict__ XW, float* __restrict__ Ssrc,
                                              float* __restrict__ Sdst, int N) {
    int t = threadIdx.x, lane = t & 63, wid = t >> 6;
    int row = blockIdx.x * 256 + wid * 64 + lane;
    int rowc = row < N ? row : N - 1;  // clamp (loads only; no write for OOB)
    const float* xp = X + (size_t)rowc * K;

    float acc[64];
    #pragma unroll
    for (int c = 0; c < 64; c++) acc[c] = 0.f;

    float4 xq = *(const float4*)xp;  // k = 0..3
    #pragma clang loop unroll(disable)
    for (int kk = 0; kk < K; kk += 4) {
        float4 xcur = xq;
        int knext = (kk + 4 < K) ? kk + 4 : 0;   // guard: no OOB read on last row
        xq = *(const float4*)(xp + knext);       // prefetch, consumed next body
        #pragma unroll
        for (int k4 = 0; k4 < 4; k4++) {
            const float* wk = W + (size_t)(kk + k4) * 64;  // wave-uniform -> s_load
            float xv = (k4 == 0) ? xcur.x : (k4 == 1) ? xcur.y : (k4 == 2) ? xcur.z : xcur.w;
            #pragma unroll
            for (int c = 0; c < 64; c++) acc[c] += xv * wk[c];
        }
    }

    if (row < N) {
        // attention logits: a_s/a_d wave-uniform -> SGPR broadcast, no shuffles
        float vs = 0.f, vd = 0.f;
        #pragma unroll
        for (int c = 0; c < 64; c++) {
            vs += acc[c] * a_s[c];
            vd += acc[c] * a_d[c];
        }
        Ssrc[row] = vs;
        Sdst[row] = vd;
        // row store: 16 dwordx4; successive stores fill each 64B line fully
        float4* op = (float4*)(XW + (size_t)row * 64);
        #pragma unroll
        for (int c4 = 0; c4 < 16; c4++)
            op[c4] = make_float4(acc[c4 * 4], acc[c4 * 4 + 1], acc[c4 * 4 + 2], acc[c4 * 4 + 3]);
    }
}

// ---------------- attention + aggregate: one wave per dst node ----------------
__global__ __launch_bounds__(256) void k_attn(const float* __restrict__ XW, const float* __restrict__ Ssrc,
                                              const float* __restrict__ Sdst, const int* __restrict__ csr,
                                              const int* __restrict__ off, const int* __restrict__ deg,
                                              const float* __restrict__ bias, float* __restrict__ H,
                                              int N, int do_relu) {
    int t = threadIdx.x, lane = t & 63, wid = t >> 6;
    int n = blockIdx.x * 4 + wid;
    if (n >= N) return;
    float sd = Sdst[n];
    int st = off[n], d = deg[n];

    // phase 1: max over edges (lanes parallel over edges); cache first 64 src/e in regs
    float eself = lrelu(Ssrc[n] + sd);
    float m = eself;
    int myS = 0;
    float myE = -1e30f;
    if (lane < d) {
        myS = csr[st + lane];
        myE = lrelu(Ssrc[myS] + sd);
        m = fmaxf(m, myE);
    }
    for (int i = 64 + lane; i < d; i += 64) {
        int s = csr[st + i];
        m = fmaxf(m, lrelu(Ssrc[s] + sd));
    }
    #pragma unroll
    for (int dd = 32; dd > 0; dd >>= 1) m = fmaxf(m, __shfl_xor(m, dd));

    // phase 2: serial over edges, lanes = feature dims
    float w0 = __expf(eself - m);
    float denom = w0;
    float acc = w0 * XW[(size_t)n * 64 + lane];
    int dcap = d < 64 ? d : 64;
    for (int i = 0; i < dcap; i++) {
        int s = __shfl(myS, i);
        float e = __shfl(myE, i);
        float w = __expf(e - m);
        denom += w;
        acc += w * XW[(size_t)s * 64 + lane];
    }
    for (int i = 64; i < d; i++) {
        int s = csr[st + i];
        float e = lrelu(Ssrc[s] + sd);
        float w = __expf(e - m);
        denom += w;
        acc += w * XW[(size_t)s * 64 + lane];
    }
    float o = acc / denom + bias[lane];
    if (do_relu) o = fmaxf(o, 0.f);
    H[(size_t)n * 64 + lane] = o;
}

// ---------------- head: out[i] = [h[u]; h[m]] . fcW + fcb ----------------
__global__ __launch_bounds__(256) void k_head(const float* __restrict__ H, const int* __restrict__ ui,
                                              const int* __restrict__ mi, const float* __restrict__ fcW,
                                              const float* __restrict__ fcb, float* __restrict__ out, int B) {
    int t = threadIdx.x, lane = t & 63, wid = t >> 6;
    int i = blockIdx.x * 4 + wid;
    if (i >= B) return;
    int u = ui[i], m = mi[i];
    float v = H[(size_t)u * 64 + lane] * fcW[lane] + H[(size_t)m * 64 + lane] * fcW[64 + lane];
    #pragma unroll
    for (int dd = 32; dd > 0; dd >>= 1) v += __shfl_xor(v, dd);
    if (lane == 0) out[i] = v + fcb[0];
}

extern "C" void kernel_launch(void* const* d_in, const int* in_sizes, int n_in,
                              void* d_out, int out_size, void* d_ws, size_t ws_size,
                              hipStream_t stream) {
    const float* x   = (const float*)d_in[0];
    const int*   ei  = (const int*)d_in[1];
    const int*   ui  = (const int*)d_in[2];
    const int*   mi  = (const int*)d_in[3];
    const float* W1  = (const float*)d_in[4];
    const float* as1 = (const float*)d_in[5];
    const float* ad1 = (const float*)d_in[6];
    const float* b1  = (const float*)d_in[7];
    const float* W2  = (const float*)d_in[8];
    const float* as2 = (const float*)d_in[9];
    const float* ad2 = (const float*)d_in[10];
    const float* b2  = (const float*)d_in[11];
    const float* fcW = (const float*)d_in[12];
    const float* fcb = (const float*)d_in[13];
    float* out = (float*)d_out;

    const int Hdim = in_sizes[5];            // 64
    const int FIN  = in_sizes[4] / Hdim;     // 256
    const int N    = in_sizes[0] / FIN;      // 100000
    const int E    = in_sizes[1] / 2;        // 1000000
    const int B    = in_sizes[2];            // 16384

    // workspace carve
    char* w = (char*)d_ws;
    auto alloc = [&](size_t bytes) -> void* {
        void* p = (void*)w;
        w += (bytes + 255) & ~(size_t)255;
        return p;
    };
    float* xw   = (float*)alloc((size_t)N * 64 * 4);
    float* hbuf = (float*)alloc((size_t)N * 64 * 4);
    float* ssrc = (float*)alloc((size_t)N * 4);
    float* sdst = (float*)alloc((size_t)N * 4);
    int* degcur = (int*)alloc((size_t)2 * N * 4);  // deg | cur contiguous
    int* deg = degcur;
    int* cur = degcur + N;
    int* offv  = (int*)alloc((size_t)N * 4);
    int* bsums = (int*)alloc((size_t)1024 * 4);
    int* csr   = (int*)alloc((size_t)E * 4);

    const int* esrc = ei;
    const int* edst = ei + E;

    // --- build CSR by dst (shared by both layers) ---
    k_zero<<<(2 * N + 1023) / 1024, 1024, 0, stream>>>(degcur, 2 * N);
    k_hist<<<(E + 255) / 256, 256, 0, stream>>>(edst, deg, E);
    int nb = (N + 1023) / 1024;
    k_scan1<<<nb, 1024, 0, stream>>>(deg, offv, bsums, N);
    k_scan2<<<1, 1024, 0, stream>>>(bsums, nb);
    k_scan3<<<nb, 1024, 0, stream>>>(offv, bsums, N);
    k_scatter<<<(E + 255) / 256, 256, 0, stream>>>(esrc, edst, offv, cur, csr, E);

    const int gemmBlocks = (N + 255) / 256;

    // --- layer 1 ---
    k_gemm<256><<<gemmBlocks, 256, 0, stream>>>(x, W1, as1, ad1, xw, ssrc, sdst, N);
    k_attn<<<(N + 3) / 4, 256, 0, stream>>>(xw, ssrc, sdst, csr, offv, deg, b1, hbuf, N, 1);

    // --- layer 2 (xw buffer reused) ---
    k_gemm<64><<<gemmBlocks, 256, 0, stream>>>(hbuf, W2, as2, ad2, xw, ssrc, sdst, N);
    k_attn<<<(N + 3) / 4, 256, 0, stream>>>(xw, ssrc, sdst, csr, offv, deg, b2, hbuf, N, 0);

    // --- head ---
    k_head<<<(B + 3) / 4, 256, 0, stream>>>(hbuf, ui, mi, fcW, fcb, out, B);
}